// Round 2
// baseline (462.705 us; speedup 1.0000x reference)
//
#include <hip/hip_runtime.h>

// B=2,H=16,S=2048,D=128 (f32 I/O; internal bf16 MFMA)
//   qk = x1·x2^T*scale + mask;  P = softmax_k(qk);  out = x3 @ P
// ws (58.7 MB): x1s=bf16(x1*scale*log2e), x2b=bf16(x2), x3s=bf16(x3*rl),
//               mbf=bf16(mask*log2e)   -> exp() is exp2()
//   k_cvt: one-time conversions (log2e folded in)
//   k_qk : rowsums C[q][k]; Q held in REGISTERS (wave-private + iter-invariant,
//          8x short8 = 32 VGPR) -> LDS = sK only (32KB) -> 3 blocks/CU.
//   k_out: QK recompute + exp2 + PV. A-operands (x1 rows, x3s rows) are
//          wave-private -> loaded global->reg directly; LDS = sK + sE (48KB)
//          -> 3 blocks/CU. No setprio, no asm cvt_pk (m240/m190 regressions).
// Grid: blockIdx.x = bh (XCD gets whole bh -> x1s/x3s L2 locality),
//       blockIdx.y = q-stripe / k-block.
// LDS swizzle: 16B chunk c of row r stored at (c ^ (r&7)) -> bank-uniform for
// both row-staging writes and column-pattern fragment reads.

typedef __attribute__((ext_vector_type(8))) short short8;
typedef __attribute__((ext_vector_type(4))) float f32x4;

#define S_LEN 2048
#define D_LEN 128
#define BH_N 32
#define SCALE_QK 0.08838834764831845f
#define LOG2E 1.4426950408889634f

__device__ __forceinline__ unsigned short f2bf(float f) {
    union { float f; unsigned int i; } v; v.f = f;
    unsigned int r = v.i + 0x7FFFu + ((v.i >> 16) & 1u);  // RNE
    return (unsigned short)(r >> 16);
}
__device__ __forceinline__ float bf2f(unsigned short u) {
    union { unsigned int i; float f; } v; v.i = ((unsigned int)u) << 16; return v.f;
}
__device__ __forceinline__ uint2 pack4bf(float4 v) {
    uint2 p;
    p.x = (unsigned)f2bf(v.x) | ((unsigned)f2bf(v.y) << 16);
    p.y = (unsigned)f2bf(v.z) | ((unsigned)f2bf(v.w) << 16);
    return p;
}

// ---------- Kernel 0: one-time f32 -> bf16 conversions ----------
__global__ void k_cvt(const float* __restrict__ x1,
                      const float* __restrict__ x2,
                      const float* __restrict__ mask,
                      unsigned short* __restrict__ x1s,
                      unsigned short* __restrict__ x2b,
                      unsigned short* __restrict__ mbf) {
    const size_t N1 = (size_t)BH_N * S_LEN * D_LEN;
    const size_t NM = (size_t)S_LEN * S_LEN;
    size_t i = ((size_t)blockIdx.x * 256 + threadIdx.x) * 4;
    const float s1 = SCALE_QK * LOG2E;
    if (i < N1) {
        float4 v = *(const float4*)&x1[i];
        v.x *= s1; v.y *= s1; v.z *= s1; v.w *= s1;
        *(uint2*)&x1s[i] = pack4bf(v);
    } else if (i < 2 * N1) {
        size_t j = i - N1;
        float4 v = *(const float4*)&x2[j];
        *(uint2*)&x2b[j] = pack4bf(v);
    } else if (i < 2 * N1 + NM) {
        size_t j = i - 2 * N1;
        float4 v = *(const float4*)&mask[j];
        v.x *= LOG2E; v.y *= LOG2E; v.z *= LOG2E; v.w *= LOG2E;
        *(uint2*)&mbf[j] = pack4bf(v);
    }
}

// ---------- Kernel 1: rowsums (C[q][k], A=x1 in regs) + x3s stripe ----------
// grid(32, 16): x = bh, y = 128-row q stripe. 4 waves, 3 blocks/CU.
// Wave w owns q rows [32w, 32w+32): acc[qb][kb], qb in {0,1}, kb in {0..7}.
__global__ __launch_bounds__(256, 3) void k_qk(
    const unsigned short* __restrict__ x1s,
    const unsigned short* __restrict__ x2b,
    const unsigned short* __restrict__ mbf,
    const float* __restrict__ x3,
    unsigned short* __restrict__ x3s)
{
    __shared__ unsigned short sK[128 * 128];  // k x d bf16 (per-iter, swizzled)
    __shared__ float sRL[128];
    const int bh = blockIdx.x;
    const int q0 = blockIdx.y * 128;
    const unsigned short* x1p = x1s + (size_t)bh * S_LEN * D_LEN;
    const unsigned short* x2p = x2b + (size_t)bh * S_LEN * D_LEN;
    const int t = threadIdx.x;
    const int w = t >> 6, lane = t & 63, quad = lane >> 4, l16 = lane & 15;

    // Q fragments in registers: rows q0+32w+16qb+l16, 16B chunk (kk*4+quad).
    // Wave-private and k-iteration-invariant -> load once, 32 VGPRs.
    short8 aq[2][4];
#pragma unroll
    for (int qb = 0; qb < 2; ++qb)
#pragma unroll
        for (int kk = 0; kk < 4; ++kk)
            aq[qb][kk] = *(const short8*)&x1p[(size_t)(q0 + 32 * w + 16 * qb + l16) * D_LEN
                                              + (kk * 4 + quad) * 8];

    float rs[8] = {0.f, 0.f, 0.f, 0.f, 0.f, 0.f, 0.f, 0.f};

    for (int k0 = 0; k0 < S_LEN; k0 += 128) {
        __syncthreads();
#pragma unroll
        for (int i = 0; i < 8; ++i) {  // stage sK (128x128), swizzled
            int idx = i * 256 + t;
            int r = idx >> 4, c = idx & 15;
            *(uint4*)&sK[r * 128 + ((c ^ (r & 7)) * 8)] =
                *(const uint4*)&x2p[(size_t)(k0 + r) * D_LEN + c * 8];
        }
        __syncthreads();

        f32x4 acc[2][8];
#pragma unroll
        for (int qb = 0; qb < 2; ++qb)
#pragma unroll
            for (int kb = 0; kb < 8; ++kb) acc[qb][kb] = (f32x4){0.f, 0.f, 0.f, 0.f};

#pragma unroll
        for (int kk = 0; kk < 4; ++kk) {
            const int sc = ((kk * 4 + quad) ^ (l16 & 7)) * 8;
            short8 b[8];
#pragma unroll
            for (int kb = 0; kb < 8; ++kb)
                b[kb] = *(const short8*)&sK[(kb * 16 + l16) * 128 + sc];
#pragma unroll
            for (int qb = 0; qb < 2; ++qb)
#pragma unroll
                for (int kb = 0; kb < 8; ++kb)
                    acc[qb][kb] = __builtin_amdgcn_mfma_f32_16x16x32_bf16(aq[qb][kk], b[kb], acc[qb][kb], 0, 0, 0);
        }

        // exp2 + rowsum; C row = q = 32w+16qb+4quad+rr, col = k = kb*16+l16
#pragma unroll
        for (int qb = 0; qb < 2; ++qb)
#pragma unroll
            for (int kb = 0; kb < 8; ++kb) {
                const size_t mrow = (size_t)(q0 + 32 * w + 16 * qb + 4 * quad) * S_LEN
                                    + k0 + kb * 16 + l16;
#pragma unroll
                for (int rr = 0; rr < 4; ++rr)
                    rs[qb * 4 + rr] += exp2f(acc[qb][kb][rr] + bf2f(mbf[mrow + (size_t)rr * S_LEN]));
            }
    }

    // each wave owns its 32 q rows: reduce over l16 (cols), write 1/sum
#pragma unroll
    for (int i = 0; i < 8; ++i) {
        float v = rs[i];
        v += __shfl_xor(v, 1); v += __shfl_xor(v, 2);
        v += __shfl_xor(v, 4); v += __shfl_xor(v, 8);
        if (l16 == 0) sRL[32 * w + 16 * (i >> 2) + 4 * quad + (i & 3)] = 1.0f / v;
    }
    __syncthreads();

    // x3s[:, q0:q0+128] = bf16(x3 * rl)
    const float* x3b = x3 + (size_t)bh * (size_t)D_LEN * S_LEN;
    unsigned short* x3sp = x3s + (size_t)bh * (size_t)D_LEN * S_LEN;
#pragma unroll
    for (int i = 0; i < 16; ++i) {
        int e = (i * 256 + t) * 4;
        int r = e >> 7, c = e & 127;
        float4 v = *(const float4*)&x3b[(size_t)r * S_LEN + q0 + c];
        v.x *= sRL[c]; v.y *= sRL[c + 1]; v.z *= sRL[c + 2]; v.w *= sRL[c + 3];
        *(uint2*)&x3sp[(size_t)r * S_LEN + q0 + c] = pack4bf(v);
    }
}

// ---------- Kernel 2: out = x3s @ exp2(QK + mask), 128-k blocks ----------
// grid(32, 16): x = bh, y = 128-col k block. 4 waves, 3 blocks/CU.
// QK: wave w owns q rows [16w,16w+16) x 128k (A from global->reg).
// PV: wave w owns d [32w,32w+32) (A from global->reg). LDS: sK + sE only.
__global__ __launch_bounds__(256, 3) void k_out(
    const unsigned short* __restrict__ x1s,
    const unsigned short* __restrict__ x2b,
    const unsigned short* __restrict__ x3s,
    const unsigned short* __restrict__ mbf,
    float* __restrict__ out)
{
    __shared__ unsigned short sK[128 * 128];  // x2 k-block (resident, swizzled)
    __shared__ unsigned short sE[128 * 64];   // E^T k x q (swizzled)
    const int bh = blockIdx.x;
    const int kb0 = blockIdx.y * 128;
    const unsigned short* x1p = x1s + (size_t)bh * S_LEN * D_LEN;
    const unsigned short* x2p = x2b + (size_t)bh * S_LEN * D_LEN;
    const unsigned short* x3p = x3s + (size_t)bh * (size_t)D_LEN * S_LEN;
    const int t = threadIdx.x;
    const int w = t >> 6, lane = t & 63, quad = lane >> 4, l16 = lane & 15;
    const int qrow = 16 * w + 4 * quad;       // q row base within tile (invariant)
    const int cE = qrow >> 3;                 // q chunk idx for sE store
    const int qoff7 = qrow & 7;               // 8B offset in chunk

#pragma unroll
    for (int i = 0; i < 8; ++i) {  // stage resident sK (128x128), swizzled
        int idx = i * 256 + t;
        int r = idx >> 4, c = idx & 15;
        *(uint4*)&sK[r * 128 + ((c ^ (r & 7)) * 8)] =
            *(const uint4*)&x2p[(size_t)(kb0 + r) * D_LEN + c * 8];
    }

    f32x4 oa[16];  // db(2) x kb(8)
#pragma unroll
    for (int i = 0; i < 16; ++i) oa[i] = (f32x4){0.f, 0.f, 0.f, 0.f};

    __syncthreads();  // sK ready

    for (int q0 = 0; q0 < S_LEN; q0 += 64) {
        // QK A-fragments: rows q0+16w+l16 (wave-private), straight from global
        short8 aq[4];
#pragma unroll
        for (int kk = 0; kk < 4; ++kk)
            aq[kk] = *(const short8*)&x1p[(size_t)(q0 + 16 * w + l16) * D_LEN
                                           + (kk * 4 + quad) * 8];

        // QK: 16q x 128k per wave
        f32x4 acc[8];
#pragma unroll
        for (int kb = 0; kb < 8; ++kb) acc[kb] = (f32x4){0.f, 0.f, 0.f, 0.f};
#pragma unroll
        for (int kk = 0; kk < 4; ++kk) {
            const int sc = ((kk * 4 + quad) ^ (l16 & 7)) * 8;
            short8 b[8];
#pragma unroll
            for (int kb = 0; kb < 8; ++kb)
                b[kb] = *(const short8*)&sK[(kb * 16 + l16) * 128 + sc];
#pragma unroll
            for (int kb = 0; kb < 8; ++kb)
                acc[kb] = __builtin_amdgcn_mfma_f32_16x16x32_bf16(aq[kk], b[kb], acc[kb], 0, 0, 0);
        }

        // exp2 + bf16 pack into regs; C row = q = qrow+rr, col = k = kb*16+l16
        uint2 pk[8];
#pragma unroll
        for (int kb = 0; kb < 8; ++kb) {
            const size_t mrow = (size_t)(q0 + qrow) * S_LEN + kb0 + kb * 16 + l16;
            float e0 = exp2f(acc[kb][0] + bf2f(mbf[mrow]));
            float e1 = exp2f(acc[kb][1] + bf2f(mbf[mrow + S_LEN]));
            float e2 = exp2f(acc[kb][2] + bf2f(mbf[mrow + 2 * S_LEN]));
            float e3 = exp2f(acc[kb][3] + bf2f(mbf[mrow + 3 * S_LEN]));
            pk[kb].x = (unsigned)f2bf(e0) | ((unsigned)f2bf(e1) << 16);
            pk[kb].y = (unsigned)f2bf(e2) | ((unsigned)f2bf(e3) << 16);
        }

        __syncthreads();  // prev PV done reading sE
#pragma unroll
        for (int kb = 0; kb < 8; ++kb) {
            const int krow = kb * 16 + l16;
            *(uint2*)&sE[krow * 64 + ((cE ^ (krow & 7)) * 8) + qoff7] = pk[kb];
        }

        // PV A-fragments: x3s rows 32w+16db+l16 (wave-private), from global;
        // issued before the barrier so latency hides under the barrier+ds_reads
        short8 ax[2][2];
#pragma unroll
        for (int db = 0; db < 2; ++db)
#pragma unroll
            for (int kk = 0; kk < 2; ++kk)
                ax[db][kk] = *(const short8*)&x3p[(size_t)(32 * w + 16 * db + l16) * S_LEN
                                                  + q0 + (kk * 4 + quad) * 8];

        __syncthreads();  // sE ready

        // PV: 32d x 128k per wave
#pragma unroll
        for (int kk = 0; kk < 2; ++kk) {
            const int sc = ((kk * 4 + quad) ^ (l16 & 7)) * 8;
            short8 b[8];
#pragma unroll
            for (int kb = 0; kb < 8; ++kb)
                b[kb] = *(const short8*)&sE[(kb * 16 + l16) * 64 + sc];
#pragma unroll
            for (int db = 0; db < 2; ++db)
#pragma unroll
                for (int kb = 0; kb < 8; ++kb)
                    oa[db * 8 + kb] = __builtin_amdgcn_mfma_f32_16x16x32_bf16(ax[db][kk], b[kb], oa[db * 8 + kb], 0, 0, 0);
        }
    }

#pragma unroll
    for (int db = 0; db < 2; ++db)
#pragma unroll
        for (int kb = 0; kb < 8; ++kb)
#pragma unroll
            for (int rr = 0; rr < 4; ++rr) {
                int d = 32 * w + 16 * db + 4 * quad + rr;
                out[((size_t)bh * D_LEN + d) * S_LEN + kb0 + kb * 16 + l16] =
                    oa[db * 8 + kb][rr];
            }
}

// ================= Fallback path (ws too small) =================
__global__ __launch_bounds__(256, 3) void k_rowsum_fb(
    const float* __restrict__ x1, const float* __restrict__ x2,
    const float* __restrict__ mask, float* __restrict__ rl)
{
    __shared__ unsigned short sQ[128 * 136];
    __shared__ unsigned short sK[64 * 136];
    const int q0 = blockIdx.x * 128;
    const int bh = blockIdx.y;
    const float* x1b = x1 + (size_t)bh * S_LEN * D_LEN;
    const float* x2b = x2 + (size_t)bh * S_LEN * D_LEN;
    const int t = threadIdx.x;
    const int w = t >> 6, lane = t & 63, quad = lane >> 4, l16 = lane & 15;
#pragma unroll
    for (int i = 0; i < 16; ++i) {
        int e = (i * 256 + t) * 4;
        int r = e >> 7, c = e & 127;
        float4 v = *(const float4*)&x1b[(size_t)(q0 + r) * D_LEN + c];
        *(uint2*)&sQ[r * 136 + c] = pack4bf(v);
    }
    float rs[8] = {0.f, 0.f, 0.f, 0.f, 0.f, 0.f, 0.f, 0.f};
    for (int k0 = 0; k0 < S_LEN; k0 += 64) {
        __syncthreads();
#pragma unroll
        for (int i = 0; i < 8; ++i) {
            int e = (i * 256 + t) * 4;
            int r = e >> 7, c = e & 127;
            float4 v = *(const float4*)&x2b[(size_t)(k0 + r) * D_LEN + c];
            *(uint2*)&sK[r * 136 + c] = pack4bf(v);
        }
        __syncthreads();
#pragma unroll
        for (int qb = 0; qb < 2; ++qb) {
            const int qrow = 32 * w + 16 * qb;
#pragma unroll
            for (int kb = 0; kb < 4; ++kb) {
                f32x4 acc = {0.f, 0.f, 0.f, 0.f};
#pragma unroll
                for (int kk = 0; kk < 4; ++kk) {
                    short8 a = *(const short8*)&sQ[(qrow + l16) * 136 + kk * 32 + quad * 8];
                    short8 b = *(const short8*)&sK[(kb * 16 + l16) * 136 + kk * 32 + quad * 8];
                    acc = __builtin_amdgcn_mfma_f32_16x16x32_bf16(a, b, acc, 0, 0, 0);
                }
                const int kg = k0 + kb * 16 + l16;
                const int qg = q0 + qrow + 4 * quad;
#pragma unroll
                for (int r = 0; r < 4; ++r) {
                    float m = mask[(size_t)(qg + r) * S_LEN + kg];
                    rs[qb * 4 + r] += __expf(acc[r] * SCALE_QK + m);
                }
            }
        }
    }
#pragma unroll
    for (int i = 0; i < 8; ++i) {
        float v = rs[i];
        v += __shfl_xor(v, 1); v += __shfl_xor(v, 2);
        v += __shfl_xor(v, 4); v += __shfl_xor(v, 8);
        if (l16 == 0) {
            int qg = q0 + 32 * w + 16 * (i >> 2) + 4 * quad + (i & 3);
            rl[(size_t)bh * S_LEN + qg] = 1.0f / v;
        }
    }
}

__global__ __launch_bounds__(256, 2) void k_out_fb(
    const float* __restrict__ x1, const float* __restrict__ x2,
    const float* __restrict__ x3, const float* __restrict__ mask,
    const float* __restrict__ rl, float* __restrict__ out)
{
    __shared__ unsigned short sK[64 * 136];
    __shared__ unsigned short sQ[64 * 136];
    __shared__ unsigned short sX[128 * 72];
    __shared__ unsigned short sE[64 * 72];
    const int kb0 = blockIdx.x * 64;
    const int bh = blockIdx.y;
    const float* x1b = x1 + (size_t)bh * S_LEN * D_LEN;
    const float* x2b = x2 + (size_t)bh * S_LEN * D_LEN;
    const float* x3b = x3 + (size_t)bh * (size_t)D_LEN * S_LEN;
    const float* rlb = rl + (size_t)bh * S_LEN;
    const int t = threadIdx.x;
    const int w = t >> 6, lane = t & 63, quad = lane >> 4, l16 = lane & 15;
#pragma unroll
    for (int i = 0; i < 8; ++i) {
        int e = (i * 256 + t) * 4;
        int r = e >> 7, c = e & 127;
        float4 v = *(const float4*)&x2b[(size_t)(kb0 + r) * D_LEN + c];
        *(uint2*)&sK[r * 136 + c] = pack4bf(v);
    }
    f32x4 oa[8];
#pragma unroll
    for (int i = 0; i < 8; ++i) oa[i] = (f32x4){0.f, 0.f, 0.f, 0.f};
    for (int q0 = 0; q0 < S_LEN; q0 += 64) {
        __syncthreads();
#pragma unroll
        for (int i = 0; i < 8; ++i) {
            int e = (i * 256 + t) * 4;
            int r = e >> 7, c = e & 127;
            float4 v = *(const float4*)&x1b[(size_t)(q0 + r) * D_LEN + c];
            *(uint2*)&sQ[r * 136 + c] = pack4bf(v);
        }
#pragma unroll
        for (int i = 0; i < 8; ++i) {
            int e = (i * 256 + t) * 4;
            int r = e >> 6, c = e & 63;
            float4 v = *(const float4*)&x3b[(size_t)r * S_LEN + q0 + c];
            *(uint2*)&sX[r * 72 + c] = pack4bf(v);
        }
        __syncthreads();
        const int qrow = 16 * w + 4 * quad;
        float rl4[4];
#pragma unroll
        for (int r = 0; r < 4; ++r) rl4[r] = rlb[q0 + qrow + r];
#pragma unroll
        for (int kb = 0; kb < 4; ++kb) {
            f32x4 acc = {0.f, 0.f, 0.f, 0.f};
#pragma unroll
            for (int kk = 0; kk < 4; ++kk) {
                short8 a = *(const short8*)&sQ[(16 * w + l16) * 136 + kk * 32 + quad * 8];
                short8 b = *(const short8*)&sK[(kb * 16 + l16) * 136 + kk * 32 + quad * 8];
                acc = __builtin_amdgcn_mfma_f32_16x16x32_bf16(a, b, acc, 0, 0, 0);
            }
            const int kg = kb0 + kb * 16 + l16;
            unsigned short e4[4];
#pragma unroll
            for (int r = 0; r < 4; ++r) {
                float m = mask[(size_t)(q0 + qrow + r) * S_LEN + kg];
                e4[r] = f2bf(__expf(acc[r] * SCALE_QK + m) * rl4[r]);
            }
            uint2 pk;
            pk.x = (unsigned)e4[0] | ((unsigned)e4[1] << 16);
            pk.y = (unsigned)e4[2] | ((unsigned)e4[3] << 16);
            *(uint2*)&sE[(kb * 16 + l16) * 72 + qrow] = pk;
        }
        __syncthreads();
#pragma unroll
        for (int db = 0; db < 2; ++db)
#pragma unroll
            for (int kb = 0; kb < 4; ++kb) {
                f32x4 a0 = oa[db * 4 + kb];
#pragma unroll
                for (int kk = 0; kk < 2; ++kk) {
                    short8 a = *(const short8*)&sX[(32 * w + 16 * db + l16) * 72 + kk * 32 + quad * 8];
                    short8 b = *(const short8*)&sE[(kb * 16 + l16) * 72 + kk * 32 + quad * 8];
                    a0 = __builtin_amdgcn_mfma_f32_16x16x32_bf16(a, b, a0, 0, 0, 0);
                }
                oa[db * 4 + kb] = a0;
            }
    }
#pragma unroll
    for (int db = 0; db < 2; ++db)
#pragma unroll
        for (int kb = 0; kb < 4; ++kb)
#pragma unroll
            for (int r = 0; r < 4; ++r) {
                int d = 32 * w + 16 * db + 4 * quad + r;
                out[((size_t)bh * D_LEN + d) * S_LEN + kb0 + kb * 16 + l16] =
                    oa[db * 4 + kb][r];
            }
}

extern "C" void kernel_launch(void* const* d_in, const int* in_sizes, int n_in,
                              void* d_out, int out_size, void* d_ws, size_t ws_size,
                              hipStream_t stream) {
    const float* x1 = (const float*)d_in[0];
    const float* x2 = (const float*)d_in[1];
    const float* x3 = (const float*)d_in[2];
    const float* mask = (const float*)d_in[3];
    float* out = (float*)d_out;

    const size_t N1 = (size_t)BH_N * S_LEN * D_LEN;
    const size_t NM = (size_t)S_LEN * S_LEN;
    const size_t need = (3 * N1 + NM) * sizeof(unsigned short);  // 58.7 MB

    if (ws_size >= need) {
        unsigned short* x1s = (unsigned short*)d_ws;
        unsigned short* x2b = x1s + N1;
        unsigned short* x3s = x2b + N1;
        unsigned short* mbf = x3s + N1;
        const size_t tot4 = (2 * N1 + NM) / 4;
        k_cvt<<<dim3((unsigned)(tot4 / 256)), dim3(256), 0, stream>>>(x1, x2, mask, x1s, x2b, mbf);
        k_qk<<<dim3(BH_N, S_LEN / 128), dim3(256), 0, stream>>>(x1s, x2b, mbf, x3, x3s);
        k_out<<<dim3(BH_N, S_LEN / 128), dim3(256), 0, stream>>>(x1s, x2b, x3s, mbf, out);
    } else {
        float* rl = (float*)d_ws;
        k_rowsum_fb<<<dim3(S_LEN / 128, BH_N), dim3(256), 0, stream>>>(x1, x2, mask, rl);
        k_out_fb<<<dim3(S_LEN / 64, BH_N), dim3(256), 0, stream>>>(x1, x2, x3, mask, rl, out);
    }
}

// Round 3
// 372.263 us; speedup vs baseline: 1.2430x; 1.2430x over previous
//
#include <hip/hip_runtime.h>

// B=2,H=16,S=2048,D=128 (f32 I/O; internal bf16 MFMA)
//   qk = x1·x2^T*scale + mask;  P = softmax_k(qk);  out = x3 @ P
// ws (58.7 MB): x1s=bf16(x1*scale), x2b=bf16(x2), x3s=bf16(x3*rl), mbf=bf16(mask)
//   k_cvt: one-time conversions (scale folded into x1s; mask plain; exp via
//          __expf = v_mul+v_exp. NOTE: exp2f without fast-math is precise OCML
//          (~10 ops) — measured regression in R1/R2, do not use.)
//   k_qk : rowsums C[q][k]. Q-frags in regs (loaded once). sK staged via regs
//          loaded ONE ITERATION AHEAD (T14 issue-early/write-late): serial
//          segment per iter is 8 ds_writes, global latency hides under MFMA+exp.
//          Masks injected into acc MID-MFMA (after kk=2): loads issue post-
//          barrier, hide under 48 MFMAs, no 64-reg prefetch array.
//   k_out: QK recompute + exp + PV. A-operands (x1 rows, x3s rows) wave-private
//          -> direct global->reg, but issued EARLY: next-iter QK A-frags + this-
//          iter masks before the QK MFMA block; PV A-frags between QK and exp.
//          LDS = sK(32K, resident) + sE(16K) -> 2 barriers/iter (was 3).
// Grid: x = q-stripe / k-block, y = bh (R1 orientation; R2's bh-clustering cut
//       FETCH 143->58MB but kernel is not BW-bound; revert for known-good).
// LDS swizzle: 16B chunk c of row r stored at (c ^ (r&7)) -> bank-uniform for
// both row-staging writes and column-pattern fragment reads.

typedef __attribute__((ext_vector_type(8))) short short8;
typedef __attribute__((ext_vector_type(4))) float f32x4;

#define S_LEN 2048
#define D_LEN 128
#define BH_N 32
#define SCALE_QK 0.08838834764831845f

__device__ __forceinline__ unsigned short f2bf(float f) {
    union { float f; unsigned int i; } v; v.f = f;
    unsigned int r = v.i + 0x7FFFu + ((v.i >> 16) & 1u);  // RNE
    return (unsigned short)(r >> 16);
}
__device__ __forceinline__ float bf2f(unsigned short u) {
    union { unsigned int i; float f; } v; v.i = ((unsigned int)u) << 16; return v.f;
}
__device__ __forceinline__ uint2 pack4bf(float4 v) {
    uint2 p;
    p.x = (unsigned)f2bf(v.x) | ((unsigned)f2bf(v.y) << 16);
    p.y = (unsigned)f2bf(v.z) | ((unsigned)f2bf(v.w) << 16);
    return p;
}

// ---------- Kernel 0: one-time f32 -> bf16 conversions ----------
__global__ void k_cvt(const float* __restrict__ x1,
                      const float* __restrict__ x2,
                      const float* __restrict__ mask,
                      unsigned short* __restrict__ x1s,
                      unsigned short* __restrict__ x2b,
                      unsigned short* __restrict__ mbf) {
    const size_t N1 = (size_t)BH_N * S_LEN * D_LEN;
    const size_t NM = (size_t)S_LEN * S_LEN;
    size_t i = ((size_t)blockIdx.x * 256 + threadIdx.x) * 4;
    if (i < N1) {
        float4 v = *(const float4*)&x1[i];
        v.x *= SCALE_QK; v.y *= SCALE_QK; v.z *= SCALE_QK; v.w *= SCALE_QK;
        *(uint2*)&x1s[i] = pack4bf(v);
    } else if (i < 2 * N1) {
        size_t j = i - N1;
        float4 v = *(const float4*)&x2[j];
        *(uint2*)&x2b[j] = pack4bf(v);
    } else if (i < 2 * N1 + NM) {
        size_t j = i - 2 * N1;
        float4 v = *(const float4*)&mask[j];
        *(uint2*)&mbf[j] = pack4bf(v);
    }
}

// ---------- Kernel 1: rowsums (C[q][k], A=x1 in regs) + x3s stripe ----------
// grid(16, 32): x = 128-row q stripe, y = bh. 4 waves, 2 blocks/CU (grid-lim).
// Wave w owns q rows [32w, 32w+32): acc[qb][kb], qb in {0,1}, kb in {0..7}.
__global__ __launch_bounds__(256, 2) void k_qk(
    const unsigned short* __restrict__ x1s,
    const unsigned short* __restrict__ x2b,
    const unsigned short* __restrict__ mbf,
    const float* __restrict__ x3,
    unsigned short* __restrict__ x3s)
{
    __shared__ unsigned short sK[128 * 128];  // k x d bf16 (per-iter, swizzled)
    __shared__ float sRL[128];
    const int q0 = blockIdx.x * 128;
    const int bh = blockIdx.y;
    const unsigned short* x1p = x1s + (size_t)bh * S_LEN * D_LEN;
    const unsigned short* x2p = x2b + (size_t)bh * S_LEN * D_LEN;
    const int t = threadIdx.x;
    const int w = t >> 6, lane = t & 63, quad = lane >> 4, l16 = lane & 15;

    // Q fragments in registers: wave-private, k-iteration-invariant. 32 VGPRs.
    short8 aq[2][4];
#pragma unroll
    for (int qb = 0; qb < 2; ++qb)
#pragma unroll
        for (int kk = 0; kk < 4; ++kk)
            aq[qb][kk] = *(const short8*)&x1p[(size_t)(q0 + 32 * w + 16 * qb + l16) * D_LEN
                                              + (kk * 4 + quad) * 8];

    // prologue: sK staging regs for k0 = 0 (one iteration ahead)
    uint4 rk[8];
#pragma unroll
    for (int i = 0; i < 8; ++i) {
        int idx = i * 256 + t;
        int r = idx >> 4, c = idx & 15;
        rk[i] = *(const uint4*)&x2p[(size_t)r * D_LEN + c * 8];
    }

    float rs[8] = {0.f, 0.f, 0.f, 0.f, 0.f, 0.f, 0.f, 0.f};

    for (int k0 = 0; k0 < S_LEN; k0 += 128) {
        __syncthreads();  // A: prev iter's MFMA reads of sK done
#pragma unroll
        for (int i = 0; i < 8; ++i) {  // write staged regs -> sK, swizzled
            int idx = i * 256 + t;
            int r = idx >> 4, c = idx & 15;
            *(uint4*)&sK[r * 128 + ((c ^ (r & 7)) * 8)] = rk[i];
        }
        __syncthreads();  // B: sK ready

        // issue next iter's sK loads (hide under MFMA+exp, full iter to land)
        const int k0n = (k0 + 128) & (S_LEN - 1);
#pragma unroll
        for (int i = 0; i < 8; ++i) {
            int idx = i * 256 + t;
            int r = idx >> 4, c = idx & 15;
            rk[i] = *(const uint4*)&x2p[(size_t)(k0n + r) * D_LEN + c * 8];
        }
        // issue mask loads (consumed mid-MFMA, hide under 48 MFMAs)
        unsigned short mld[2][8][4];
#pragma unroll
        for (int qb = 0; qb < 2; ++qb)
#pragma unroll
            for (int kb = 0; kb < 8; ++kb)
#pragma unroll
                for (int rr = 0; rr < 4; ++rr)
                    mld[qb][kb][rr] =
                        mbf[(size_t)(q0 + 32 * w + 16 * qb + 4 * quad + rr) * S_LEN
                            + k0 + kb * 16 + l16];

        f32x4 acc[2][8];
#pragma unroll
        for (int qb = 0; qb < 2; ++qb)
#pragma unroll
            for (int kb = 0; kb < 8; ++kb) acc[qb][kb] = (f32x4){0.f, 0.f, 0.f, 0.f};

#pragma unroll
        for (int kk = 0; kk < 4; ++kk) {
            const int sc = ((kk * 4 + quad) ^ (l16 & 7)) * 8;
            short8 b[8];
#pragma unroll
            for (int kb = 0; kb < 8; ++kb)
                b[kb] = *(const short8*)&sK[(kb * 16 + l16) * 128 + sc];
#pragma unroll
            for (int qb = 0; qb < 2; ++qb)
#pragma unroll
                for (int kb = 0; kb < 8; ++kb)
                    acc[qb][kb] = __builtin_amdgcn_mfma_f32_16x16x32_bf16(aq[qb][kk], b[kb], acc[qb][kb], 0, 0, 0);
            if (kk == 2) {  // inject mask adds mid-chain (loads landed by now)
#pragma unroll
                for (int qb = 0; qb < 2; ++qb)
#pragma unroll
                    for (int kb = 0; kb < 8; ++kb)
#pragma unroll
                        for (int rr = 0; rr < 4; ++rr)
                            acc[qb][kb][rr] += bf2f(mld[qb][kb][rr]);
            }
        }

        // exp + rowsum; C row = q = 32w+16qb+4quad+rr, col = k = kb*16+l16
#pragma unroll
        for (int qb = 0; qb < 2; ++qb)
#pragma unroll
            for (int kb = 0; kb < 8; ++kb)
#pragma unroll
                for (int rr = 0; rr < 4; ++rr)
                    rs[qb * 4 + rr] += __expf(acc[qb][kb][rr]);
    }

    // each wave owns its 32 q rows: reduce over l16 (cols), write 1/sum
#pragma unroll
    for (int i = 0; i < 8; ++i) {
        float v = rs[i];
        v += __shfl_xor(v, 1); v += __shfl_xor(v, 2);
        v += __shfl_xor(v, 4); v += __shfl_xor(v, 8);
        if (l16 == 0) sRL[32 * w + 16 * (i >> 2) + 4 * quad + (i & 3)] = 1.0f / v;
    }
    __syncthreads();

    // x3s[:, q0:q0+128] = bf16(x3 * rl)
    const float* x3b = x3 + (size_t)bh * (size_t)D_LEN * S_LEN;
    unsigned short* x3sp = x3s + (size_t)bh * (size_t)D_LEN * S_LEN;
#pragma unroll
    for (int i = 0; i < 16; ++i) {
        int e = (i * 256 + t) * 4;
        int r = e >> 7, c = e & 127;
        float4 v = *(const float4*)&x3b[(size_t)r * S_LEN + q0 + c];
        v.x *= sRL[c]; v.y *= sRL[c + 1]; v.z *= sRL[c + 2]; v.w *= sRL[c + 3];
        *(uint2*)&x3sp[(size_t)r * S_LEN + q0 + c] = pack4bf(v);
    }
}

// ---------- Kernel 2: out = x3s @ exp(QK + mask), 128-k blocks ----------
// grid(16, 32): x = 128-col k block, y = bh. 4 waves, 2 blocks/CU.
// QK: wave w owns q rows [16w,16w+16) x 128k (A regs, prefetched 1 iter ahead).
// PV: wave w owns d [32w,32w+32) (A regs, issued between QK and exp).
__global__ __launch_bounds__(256, 2) void k_out(
    const unsigned short* __restrict__ x1s,
    const unsigned short* __restrict__ x2b,
    const unsigned short* __restrict__ x3s,
    const unsigned short* __restrict__ mbf,
    float* __restrict__ out)
{
    __shared__ unsigned short sK[128 * 128];  // x2 k-block (resident, swizzled)
    __shared__ unsigned short sE[128 * 64];   // E^T k x q (swizzled)
    const int kb0 = blockIdx.x * 128;
    const int bh = blockIdx.y;
    const unsigned short* x1p = x1s + (size_t)bh * S_LEN * D_LEN;
    const unsigned short* x2p = x2b + (size_t)bh * S_LEN * D_LEN;
    const unsigned short* x3p = x3s + (size_t)bh * (size_t)D_LEN * S_LEN;
    const int t = threadIdx.x;
    const int w = t >> 6, lane = t & 63, quad = lane >> 4, l16 = lane & 15;
    const int qrow = 16 * w + 4 * quad;       // q row base within tile (invariant)
    const int cE = qrow >> 3;                 // q chunk idx for sE store
    const int qoff7 = qrow & 7;               // 8B offset in chunk

#pragma unroll
    for (int i = 0; i < 8; ++i) {  // stage resident sK (128x128), swizzled
        int idx = i * 256 + t;
        int r = idx >> 4, c = idx & 15;
        *(uint4*)&sK[r * 128 + ((c ^ (r & 7)) * 8)] =
            *(const uint4*)&x2p[(size_t)(kb0 + r) * D_LEN + c * 8];
    }

    f32x4 oa[16];  // db(2) x kb(8)
#pragma unroll
    for (int i = 0; i < 16; ++i) oa[i] = (f32x4){0.f, 0.f, 0.f, 0.f};

    // prologue: QK A-frags for q0 = 0 (one iteration ahead)
    short8 aq[4];
#pragma unroll
    for (int kk = 0; kk < 4; ++kk)
        aq[kk] = *(const short8*)&x1p[(size_t)(16 * w + l16) * D_LEN + (kk * 4 + quad) * 8];

    __syncthreads();  // sK ready

    for (int q0 = 0; q0 < S_LEN; q0 += 64) {
        // issue this iter's mask loads (consumed in exp, hide under QK MFMAs)
        unsigned short mpf[8][4];
#pragma unroll
        for (int kb = 0; kb < 8; ++kb)
#pragma unroll
            for (int rr = 0; rr < 4; ++rr)
                mpf[kb][rr] = mbf[(size_t)(q0 + qrow + rr) * S_LEN + kb0 + kb * 16 + l16];

        // issue next iter's QK A-frag loads (full iter to land)
        const int q0n = (q0 + 64) & (S_LEN - 1);
        short8 aqn[4];
#pragma unroll
        for (int kk = 0; kk < 4; ++kk)
            aqn[kk] = *(const short8*)&x1p[(size_t)(q0n + 16 * w + l16) * D_LEN
                                            + (kk * 4 + quad) * 8];

        // QK: 16q x 128k per wave
        f32x4 acc[8];
#pragma unroll
        for (int kb = 0; kb < 8; ++kb) acc[kb] = (f32x4){0.f, 0.f, 0.f, 0.f};
#pragma unroll
        for (int kk = 0; kk < 4; ++kk) {
            const int sc = ((kk * 4 + quad) ^ (l16 & 7)) * 8;
            short8 b[8];
#pragma unroll
            for (int kb = 0; kb < 8; ++kb)
                b[kb] = *(const short8*)&sK[(kb * 16 + l16) * 128 + sc];
#pragma unroll
            for (int kb = 0; kb < 8; ++kb)
                acc[kb] = __builtin_amdgcn_mfma_f32_16x16x32_bf16(aq[kk], b[kb], acc[kb], 0, 0, 0);
        }

        // issue PV A-frag loads (consumed after next barrier, hide under exp)
        short8 ax[2][2];
#pragma unroll
        for (int db = 0; db < 2; ++db)
#pragma unroll
            for (int kk = 0; kk < 2; ++kk)
                ax[db][kk] = *(const short8*)&x3p[(size_t)(32 * w + 16 * db + l16) * S_LEN
                                                  + q0 + (kk * 4 + quad) * 8];

        // exp + bf16 pack; C row = q = qrow+rr, col = k = kb*16+l16
        uint2 pk[8];
#pragma unroll
        for (int kb = 0; kb < 8; ++kb) {
            float e0 = __expf(acc[kb][0] + bf2f(mpf[kb][0]));
            float e1 = __expf(acc[kb][1] + bf2f(mpf[kb][1]));
            float e2 = __expf(acc[kb][2] + bf2f(mpf[kb][2]));
            float e3 = __expf(acc[kb][3] + bf2f(mpf[kb][3]));
            pk[kb].x = (unsigned)f2bf(e0) | ((unsigned)f2bf(e1) << 16);
            pk[kb].y = (unsigned)f2bf(e2) | ((unsigned)f2bf(e3) << 16);
        }

        __syncthreads();  // #1: prev PV done reading sE
#pragma unroll
        for (int kb = 0; kb < 8; ++kb) {
            const int krow = kb * 16 + l16;
            *(uint2*)&sE[krow * 64 + ((cE ^ (krow & 7)) * 8) + qoff7] = pk[kb];
        }
        __syncthreads();  // #2: sE ready

        // PV: 32d x 128k per wave
#pragma unroll
        for (int kk = 0; kk < 2; ++kk) {
            const int sc = ((kk * 4 + quad) ^ (l16 & 7)) * 8;
            short8 b[8];
#pragma unroll
            for (int kb = 0; kb < 8; ++kb)
                b[kb] = *(const short8*)&sE[(kb * 16 + l16) * 64 + sc];
#pragma unroll
            for (int db = 0; db < 2; ++db)
#pragma unroll
                for (int kb = 0; kb < 8; ++kb)
                    oa[db * 8 + kb] = __builtin_amdgcn_mfma_f32_16x16x32_bf16(ax[db][kk], b[kb], oa[db * 8 + kb], 0, 0, 0);
        }

#pragma unroll
        for (int kk = 0; kk < 4; ++kk) aq[kk] = aqn[kk];
    }

#pragma unroll
    for (int db = 0; db < 2; ++db)
#pragma unroll
        for (int kb = 0; kb < 8; ++kb)
#pragma unroll
            for (int rr = 0; rr < 4; ++rr) {
                int d = 32 * w + 16 * db + 4 * quad + rr;
                out[((size_t)bh * D_LEN + d) * S_LEN + kb0 + kb * 16 + l16] =
                    oa[db * 8 + kb][rr];
            }
}

// ================= Fallback path (ws too small) =================
__global__ __launch_bounds__(256, 3) void k_rowsum_fb(
    const float* __restrict__ x1, const float* __restrict__ x2,
    const float* __restrict__ mask, float* __restrict__ rl)
{
    __shared__ unsigned short sQ[128 * 136];
    __shared__ unsigned short sK[64 * 136];
    const int q0 = blockIdx.x * 128;
    const int bh = blockIdx.y;
    const float* x1b = x1 + (size_t)bh * S_LEN * D_LEN;
    const float* x2b = x2 + (size_t)bh * S_LEN * D_LEN;
    const int t = threadIdx.x;
    const int w = t >> 6, lane = t & 63, quad = lane >> 4, l16 = lane & 15;
#pragma unroll
    for (int i = 0; i < 16; ++i) {
        int e = (i * 256 + t) * 4;
        int r = e >> 7, c = e & 127;
        float4 v = *(const float4*)&x1b[(size_t)(q0 + r) * D_LEN + c];
        *(uint2*)&sQ[r * 136 + c] = pack4bf(v);
    }
    float rs[8] = {0.f, 0.f, 0.f, 0.f, 0.f, 0.f, 0.f, 0.f};
    for (int k0 = 0; k0 < S_LEN; k0 += 64) {
        __syncthreads();
#pragma unroll
        for (int i = 0; i < 8; ++i) {
            int e = (i * 256 + t) * 4;
            int r = e >> 7, c = e & 127;
            float4 v = *(const float4*)&x2b[(size_t)(k0 + r) * D_LEN + c];
            *(uint2*)&sK[r * 136 + c] = pack4bf(v);
        }
        __syncthreads();
#pragma unroll
        for (int qb = 0; qb < 2; ++qb) {
            const int qrow = 32 * w + 16 * qb;
#pragma unroll
            for (int kb = 0; kb < 4; ++kb) {
                f32x4 acc = {0.f, 0.f, 0.f, 0.f};
#pragma unroll
                for (int kk = 0; kk < 4; ++kk) {
                    short8 a = *(const short8*)&sQ[(qrow + l16) * 136 + kk * 32 + quad * 8];
                    short8 b = *(const short8*)&sK[(kb * 16 + l16) * 136 + kk * 32 + quad * 8];
                    acc = __builtin_amdgcn_mfma_f32_16x16x32_bf16(a, b, acc, 0, 0, 0);
                }
                const int kg = k0 + kb * 16 + l16;
                const int qg = q0 + qrow + 4 * quad;
#pragma unroll
                for (int r = 0; r < 4; ++r) {
                    float m = mask[(size_t)(qg + r) * S_LEN + kg];
                    rs[qb * 4 + r] += __expf(acc[r] * SCALE_QK + m);
                }
            }
        }
    }
#pragma unroll
    for (int i = 0; i < 8; ++i) {
        float v = rs[i];
        v += __shfl_xor(v, 1); v += __shfl_xor(v, 2);
        v += __shfl_xor(v, 4); v += __shfl_xor(v, 8);
        if (l16 == 0) {
            int qg = q0 + 32 * w + 16 * (i >> 2) + 4 * quad + (i & 3);
            rl[(size_t)bh * S_LEN + qg] = 1.0f / v;
        }
    }
}

__global__ __launch_bounds__(256, 2) void k_out_fb(
    const float* __restrict__ x1, const float* __restrict__ x2,
    const float* __restrict__ x3, const float* __restrict__ mask,
    const float* __restrict__ rl, float* __restrict__ out)
{
    __shared__ unsigned short sK[64 * 136];
    __shared__ unsigned short sQ[64 * 136];
    __shared__ unsigned short sX[128 * 72];
    __shared__ unsigned short sE[64 * 72];
    const int kb0 = blockIdx.x * 64;
    const int bh = blockIdx.y;
    const float* x1b = x1 + (size_t)bh * S_LEN * D_LEN;
    const float* x2b = x2 + (size_t)bh * S_LEN * D_LEN;
    const float* x3b = x3 + (size_t)bh * (size_t)D_LEN * S_LEN;
    const float* rlb = rl + (size_t)bh * S_LEN;
    const int t = threadIdx.x;
    const int w = t >> 6, lane = t & 63, quad = lane >> 4, l16 = lane & 15;
#pragma unroll
    for (int i = 0; i < 8; ++i) {
        int e = (i * 256 + t) * 4;
        int r = e >> 7, c = e & 127;
        float4 v = *(const float4*)&x2b[(size_t)(kb0 + r) * D_LEN + c];
        *(uint2*)&sK[r * 136 + c] = pack4bf(v);
    }
    f32x4 oa[8];
#pragma unroll
    for (int i = 0; i < 8; ++i) oa[i] = (f32x4){0.f, 0.f, 0.f, 0.f};
    for (int q0 = 0; q0 < S_LEN; q0 += 64) {
        __syncthreads();
#pragma unroll
        for (int i = 0; i < 8; ++i) {
            int e = (i * 256 + t) * 4;
            int r = e >> 7, c = e & 127;
            float4 v = *(const float4*)&x1b[(size_t)(q0 + r) * D_LEN + c];
            *(uint2*)&sQ[r * 136 + c] = pack4bf(v);
        }
#pragma unroll
        for (int i = 0; i < 8; ++i) {
            int e = (i * 256 + t) * 4;
            int r = e >> 6, c = e & 63;
            float4 v = *(const float4*)&x3b[(size_t)r * S_LEN + q0 + c];
            *(uint2*)&sX[r * 72 + c] = pack4bf(v);
        }
        __syncthreads();
        const int qrow = 16 * w + 4 * quad;
        float rl4[4];
#pragma unroll
        for (int r = 0; r < 4; ++r) rl4[r] = rlb[q0 + qrow + r];
#pragma unroll
        for (int kb = 0; kb < 4; ++kb) {
            f32x4 acc = {0.f, 0.f, 0.f, 0.f};
#pragma unroll
            for (int kk = 0; kk < 4; ++kk) {
                short8 a = *(const short8*)&sQ[(16 * w + l16) * 136 + kk * 32 + quad * 8];
                short8 b = *(const short8*)&sK[(kb * 16 + l16) * 136 + kk * 32 + quad * 8];
                acc = __builtin_amdgcn_mfma_f32_16x16x32_bf16(a, b, acc, 0, 0, 0);
            }
            const int kg = kb0 + kb * 16 + l16;
            unsigned short e4[4];
#pragma unroll
            for (int r = 0; r < 4; ++r) {
                float m = mask[(size_t)(q0 + qrow + r) * S_LEN + kg];
                e4[r] = f2bf(__expf(acc[r] * SCALE_QK + m) * rl4[r]);
            }
            uint2 pk;
            pk.x = (unsigned)e4[0] | ((unsigned)e4[1] << 16);
            pk.y = (unsigned)e4[2] | ((unsigned)e4[3] << 16);
            *(uint2*)&sE[(kb * 16 + l16) * 72 + qrow] = pk;
        }
        __syncthreads();
#pragma unroll
        for (int db = 0; db < 2; ++db)
#pragma unroll
            for (int kb = 0; kb < 4; ++kb) {
                f32x4 a0 = oa[db * 4 + kb];
#pragma unroll
                for (int kk = 0; kk < 2; ++kk) {
                    short8 a = *(const short8*)&sX[(32 * w + 16 * db + l16) * 72 + kk * 32 + quad * 8];
                    short8 b = *(const short8*)&sE[(kb * 16 + l16) * 72 + kk * 32 + quad * 8];
                    a0 = __builtin_amdgcn_mfma_f32_16x16x32_bf16(a, b, a0, 0, 0, 0);
                }
                oa[db * 4 + kb] = a0;
            }
    }
#pragma unroll
    for (int db = 0; db < 2; ++db)
#pragma unroll
        for (int kb = 0; kb < 4; ++kb)
#pragma unroll
            for (int r = 0; r < 4; ++r) {
                int d = 32 * w + 16 * db + 4 * quad + r;
                out[((size_t)bh * D_LEN + d) * S_LEN + kb0 + kb * 16 + l16] =
                    oa[db * 4 + kb][r];
            }
}

extern "C" void kernel_launch(void* const* d_in, const int* in_sizes, int n_in,
                              void* d_out, int out_size, void* d_ws, size_t ws_size,
                              hipStream_t stream) {
    const float* x1 = (const float*)d_in[0];
    const float* x2 = (const float*)d_in[1];
    const float* x3 = (const float*)d_in[2];
    const float* mask = (const float*)d_in[3];
    float* out = (float*)d_out;

    const size_t N1 = (size_t)BH_N * S_LEN * D_LEN;
    const size_t NM = (size_t)S_LEN * S_LEN;
    const size_t need = (3 * N1 + NM) * sizeof(unsigned short);  // 58.7 MB

    if (ws_size >= need) {
        unsigned short* x1s = (unsigned short*)d_ws;
        unsigned short* x2b = x1s + N1;
        unsigned short* x3s = x2b + N1;
        unsigned short* mbf = x3s + N1;
        const size_t tot4 = (2 * N1 + NM) / 4;
        k_cvt<<<dim3((unsigned)(tot4 / 256)), dim3(256), 0, stream>>>(x1, x2, mask, x1s, x2b, mbf);
        k_qk<<<dim3(S_LEN / 128, BH_N), dim3(256), 0, stream>>>(x1s, x2b, mbf, x3, x3s);
        k_out<<<dim3(S_LEN / 128, BH_N), dim3(256), 0, stream>>>(x1s, x2b, x3s, mbf, out);
    } else {
        float* rl = (float*)d_ws;
        k_rowsum_fb<<<dim3(S_LEN / 128, BH_N), dim3(256), 0, stream>>>(x1, x2, mask, rl);
        k_out_fb<<<dim3(S_LEN / 64, BH_N), dim3(256), 0, stream>>>(x1, x2, x3, mask, rl, out);
    }
}

// Round 4
// 302.290 us; speedup vs baseline: 1.5307x; 1.2315x over previous
//
#include <hip/hip_runtime.h>

// B=2,H=16,S=2048,D=128 (f32 I/O; internal bf16 MFMA)
//   qk = x1·x2^T*scale + mask;  P = softmax_k(qk);  out = x3 @ P
// ws (58.7 MB): x1s=bf16(x1*scale), x2b=bf16(x2), x3s=bf16(x3*rl), mbf=bf16(mask)
//   k_cvt: one-time conversions (scale folded into x1s)
//   k_qk : rowsums, C[q][k] orientation (A=x1 from resident LDS sQ). Masks
//          loaded INLINE in the exp phase (no prefetch arrays — R3's staged
//          arrays were demoted to scratch: WRITE_SIZE 226MB vs 17MB expected,
//          VGPR 92 << live set). Per-wave shfl_xor rowsum reduce.
//          exp via __expf (exp2f w/o fast-math = precise OCML, ~10 ops; R1/R2
//          measured regression).
//   k_out: R0's 113µs version, byte-identical (best measured). LDS-staged
//          sQ/sX/sK/sE, inline scalar mask loads, manual RNE pack, __expf.
// LDS swizzle: 16B chunk c of row r stored at (c ^ (r&7)) -> bank-uniform for
// both row-staging writes and column-pattern fragment reads.

typedef __attribute__((ext_vector_type(8))) short short8;
typedef __attribute__((ext_vector_type(4))) float f32x4;

#define S_LEN 2048
#define D_LEN 128
#define BH_N 32
#define SCALE_QK 0.08838834764831845f

__device__ __forceinline__ unsigned short f2bf(float f) {
    union { float f; unsigned int i; } v; v.f = f;
    unsigned int r = v.i + 0x7FFFu + ((v.i >> 16) & 1u);  // RNE
    return (unsigned short)(r >> 16);
}
__device__ __forceinline__ float bf2f(unsigned short u) {
    union { unsigned int i; float f; } v; v.i = ((unsigned int)u) << 16; return v.f;
}
__device__ __forceinline__ uint2 pack4bf(float4 v) {
    uint2 p;
    p.x = (unsigned)f2bf(v.x) | ((unsigned)f2bf(v.y) << 16);
    p.y = (unsigned)f2bf(v.z) | ((unsigned)f2bf(v.w) << 16);
    return p;
}

// ---------- Kernel 0: one-time f32 -> bf16 conversions ----------
__global__ void k_cvt(const float* __restrict__ x1,
                      const float* __restrict__ x2,
                      const float* __restrict__ mask,
                      unsigned short* __restrict__ x1s,
                      unsigned short* __restrict__ x2b,
                      unsigned short* __restrict__ mbf) {
    const size_t N1 = (size_t)BH_N * S_LEN * D_LEN;
    const size_t NM = (size_t)S_LEN * S_LEN;
    size_t i = ((size_t)blockIdx.x * 256 + threadIdx.x) * 4;
    if (i < N1) {
        float4 v = *(const float4*)&x1[i];
        v.x *= SCALE_QK; v.y *= SCALE_QK; v.z *= SCALE_QK; v.w *= SCALE_QK;
        *(uint2*)&x1s[i] = pack4bf(v);
    } else if (i < 2 * N1) {
        size_t j = i - N1;
        float4 v = *(const float4*)&x2[j];
        *(uint2*)&x2b[j] = pack4bf(v);
    } else if (i < 2 * N1 + NM) {
        size_t j = i - 2 * N1;
        float4 v = *(const float4*)&mask[j];
        *(uint2*)&mbf[j] = pack4bf(v);
    }
}

// ---------- Kernel 1: rowsums (C[q][k], A=x1 from LDS) + x3s stripe ----------
// grid(16, 32): x = 128-row q stripe, y = bh. 4 waves.
// Wave w owns q rows [32w, 32w+32): acc[qb][kb], qb in {0,1}, kb in {0..7}.
// Mask loads inline in exp phase: row q quad-uniform (4 rows/instr), col k
// l16-contiguous (32 B) -> coalesced, no register-staged arrays.
__global__ __launch_bounds__(256, 2) void k_qk(
    const unsigned short* __restrict__ x1s,
    const unsigned short* __restrict__ x2b,
    const unsigned short* __restrict__ mbf,
    const float* __restrict__ x3,
    unsigned short* __restrict__ x3s)
{
    __shared__ unsigned short sQ[128 * 128];  // q x d bf16 (resident, swizzled)
    __shared__ unsigned short sK[128 * 128];  // k x d bf16 (per-iter, swizzled)
    __shared__ float sRL[128];
    const int q0 = blockIdx.x * 128;
    const int bh = blockIdx.y;
    const unsigned short* x1p = x1s + (size_t)bh * S_LEN * D_LEN;
    const unsigned short* x2p = x2b + (size_t)bh * S_LEN * D_LEN;
    const int t = threadIdx.x;
    const int w = t >> 6, lane = t & 63, quad = lane >> 4, l16 = lane & 15;

#pragma unroll
    for (int i = 0; i < 8; ++i) {  // stage resident sQ (128x128), swizzled
        int idx = i * 256 + t;
        int r = idx >> 4, c = idx & 15;
        *(uint4*)&sQ[r * 128 + ((c ^ (r & 7)) * 8)] =
            *(const uint4*)&x1p[(size_t)(q0 + r) * D_LEN + c * 8];
    }

    float rs[8] = {0.f, 0.f, 0.f, 0.f, 0.f, 0.f, 0.f, 0.f};

    for (int k0 = 0; k0 < S_LEN; k0 += 128) {
        __syncthreads();
#pragma unroll
        for (int i = 0; i < 8; ++i) {  // stage sK (128x128), swizzled
            int idx = i * 256 + t;
            int r = idx >> 4, c = idx & 15;
            *(uint4*)&sK[r * 128 + ((c ^ (r & 7)) * 8)] =
                *(const uint4*)&x2p[(size_t)(k0 + r) * D_LEN + c * 8];
        }
        __syncthreads();

        f32x4 acc[2][8];
#pragma unroll
        for (int qb = 0; qb < 2; ++qb)
#pragma unroll
            for (int kb = 0; kb < 8; ++kb) acc[qb][kb] = (f32x4){0.f, 0.f, 0.f, 0.f};

#pragma unroll
        for (int kk = 0; kk < 4; ++kk) {
            const int sc = ((kk * 4 + quad) ^ (l16 & 7)) * 8;
            short8 a[2];
#pragma unroll
            for (int qb = 0; qb < 2; ++qb)
                a[qb] = *(const short8*)&sQ[(32 * w + 16 * qb + l16) * 128 + sc];
            short8 b[8];
#pragma unroll
            for (int kb = 0; kb < 8; ++kb)
                b[kb] = *(const short8*)&sK[(kb * 16 + l16) * 128 + sc];
#pragma unroll
            for (int qb = 0; qb < 2; ++qb)
#pragma unroll
                for (int kb = 0; kb < 8; ++kb)
                    acc[qb][kb] = __builtin_amdgcn_mfma_f32_16x16x32_bf16(a[qb], b[kb], acc[qb][kb], 0, 0, 0);
        }

        // exp + rowsum, masks inline; C row = q = 32w+16qb+4quad+rr, col = kb*16+l16
#pragma unroll
        for (int qb = 0; qb < 2; ++qb)
#pragma unroll
            for (int kb = 0; kb < 8; ++kb) {
                const size_t mrow = (size_t)(q0 + 32 * w + 16 * qb + 4 * quad) * S_LEN
                                    + k0 + kb * 16 + l16;
#pragma unroll
                for (int rr = 0; rr < 4; ++rr)
                    rs[qb * 4 + rr] += __expf(acc[qb][kb][rr] + bf2f(mbf[mrow + (size_t)rr * S_LEN]));
            }
    }

    // each wave owns its 32 q rows: reduce over l16 (cols), write 1/sum
#pragma unroll
    for (int i = 0; i < 8; ++i) {
        float v = rs[i];
        v += __shfl_xor(v, 1); v += __shfl_xor(v, 2);
        v += __shfl_xor(v, 4); v += __shfl_xor(v, 8);
        if (l16 == 0) sRL[32 * w + 16 * (i >> 2) + 4 * quad + (i & 3)] = 1.0f / v;
    }
    __syncthreads();

    // x3s[:, q0:q0+128] = bf16(x3 * rl)
    const float* x3b = x3 + (size_t)bh * (size_t)D_LEN * S_LEN;
    unsigned short* x3sp = x3s + (size_t)bh * (size_t)D_LEN * S_LEN;
#pragma unroll
    for (int i = 0; i < 16; ++i) {
        int e = (i * 256 + t) * 4;
        int r = e >> 7, c = e & 127;
        float4 v = *(const float4*)&x3b[(size_t)r * S_LEN + q0 + c];
        v.x *= sRL[c]; v.y *= sRL[c + 1]; v.z *= sRL[c + 2]; v.w *= sRL[c + 3];
        *(uint2*)&x3sp[(size_t)r * S_LEN + q0 + c] = pack4bf(v);
    }
}

// ---------- Kernel 2: out = x3s @ exp(QK + mask), 128-k blocks ----------
// R0's 113µs version, byte-identical.
// grid(16, 32): x = 128-col k block, y = bh. 4 waves.
// QK: wave w owns q rows [16w,16w+16) x 128k. PV: wave w owns d [32w,32w+32).
__global__ __launch_bounds__(256, 2) void k_out(
    const unsigned short* __restrict__ x1s,
    const unsigned short* __restrict__ x2b,
    const unsigned short* __restrict__ x3s,
    const unsigned short* __restrict__ mbf,
    float* __restrict__ out)
{
    __shared__ unsigned short sK[128 * 128];  // x2 k-block (resident, swizzled)
    __shared__ unsigned short sQ[64 * 128];   // x1 q-tile (swizzled)
    __shared__ unsigned short sX[128 * 64];   // x3s tile d x q (swizzled)
    __shared__ unsigned short sE[128 * 64];   // E^T k x q (swizzled)
    const int kb0 = blockIdx.x * 128;
    const int bh = blockIdx.y;
    const unsigned short* x1p = x1s + (size_t)bh * S_LEN * D_LEN;
    const unsigned short* x2p = x2b + (size_t)bh * S_LEN * D_LEN;
    const unsigned short* x3p = x3s + (size_t)bh * (size_t)D_LEN * S_LEN;
    const int t = threadIdx.x;
    const int w = t >> 6, lane = t & 63, quad = lane >> 4, l16 = lane & 15;

#pragma unroll
    for (int i = 0; i < 8; ++i) {  // stage resident sK (128x128), swizzled
        int idx = i * 256 + t;
        int r = idx >> 4, c = idx & 15;
        *(uint4*)&sK[r * 128 + ((c ^ (r & 7)) * 8)] =
            *(const uint4*)&x2p[(size_t)(kb0 + r) * D_LEN + c * 8];
    }

    f32x4 oa[16];  // db(2) x kb(8)
#pragma unroll
    for (int i = 0; i < 16; ++i) oa[i] = (f32x4){0.f, 0.f, 0.f, 0.f};

    for (int q0 = 0; q0 < S_LEN; q0 += 64) {
        __syncthreads();
#pragma unroll
        for (int i = 0; i < 4; ++i) {  // stage sQ (64x128), swizzled
            int idx = i * 256 + t;
            int r = idx >> 4, c = idx & 15;
            *(uint4*)&sQ[r * 128 + ((c ^ (r & 7)) * 8)] =
                *(const uint4*)&x1p[(size_t)(q0 + r) * D_LEN + c * 8];
        }
#pragma unroll
        for (int i = 0; i < 4; ++i) {  // stage sX (128d x 64q), swizzled
            int idx = i * 256 + t;
            int r = idx >> 3, c = idx & 7;
            *(uint4*)&sX[r * 64 + ((c ^ (r & 7)) * 8)] =
                *(const uint4*)&x3p[(size_t)r * S_LEN + q0 + c * 8];
        }
        __syncthreads();

        // QK: 16q x 128k per wave
        f32x4 acc[8];
#pragma unroll
        for (int kb = 0; kb < 8; ++kb) acc[kb] = (f32x4){0.f, 0.f, 0.f, 0.f};
#pragma unroll
        for (int kk = 0; kk < 4; ++kk) {
            const int sc = ((kk * 4 + quad) ^ (l16 & 7)) * 8;
            short8 a = *(const short8*)&sQ[(16 * w + l16) * 128 + sc];
            short8 b[8];
#pragma unroll
            for (int kb = 0; kb < 8; ++kb)
                b[kb] = *(const short8*)&sK[(kb * 16 + l16) * 128 + sc];
#pragma unroll
            for (int kb = 0; kb < 8; ++kb)
                acc[kb] = __builtin_amdgcn_mfma_f32_16x16x32_bf16(a, b[kb], acc[kb], 0, 0, 0);
        }
        // exp + sE^T store; C row = q = 16w+4quad+r, col = k = kb*16+l16
        const int qrow = 16 * w + 4 * quad;
        const int qoff7 = (16 * w + 4 * quad) & 7;          // 8B offset in chunk
        const int cE = (16 * w + 4 * quad) >> 3;            // q chunk idx
#pragma unroll
        for (int kb = 0; kb < 8; ++kb) {
            const int kg = kb0 + kb * 16 + l16;
            unsigned short e4[4];
#pragma unroll
            for (int r = 0; r < 4; ++r) {
                float m = bf2f(mbf[(size_t)(q0 + qrow + r) * S_LEN + kg]);
                e4[r] = f2bf(__expf(acc[kb][r] + m));
            }
            uint2 pk;
            pk.x = (unsigned)e4[0] | ((unsigned)e4[1] << 16);
            pk.y = (unsigned)e4[2] | ((unsigned)e4[3] << 16);
            const int krow = kb * 16 + l16;
            *(uint2*)&sE[krow * 64 + ((cE ^ (krow & 7)) * 8) + qoff7] = pk;
        }
        __syncthreads();

        // PV: 32d x 128k per wave
#pragma unroll
        for (int kk = 0; kk < 2; ++kk) {
            const int sc = ((kk * 4 + quad) ^ (l16 & 7)) * 8;
            short8 a[2];
#pragma unroll
            for (int db = 0; db < 2; ++db)
                a[db] = *(const short8*)&sX[(32 * w + 16 * db + l16) * 64 + sc];
            short8 b[8];
#pragma unroll
            for (int kb = 0; kb < 8; ++kb)
                b[kb] = *(const short8*)&sE[(kb * 16 + l16) * 64 + sc];
#pragma unroll
            for (int db = 0; db < 2; ++db)
#pragma unroll
                for (int kb = 0; kb < 8; ++kb)
                    oa[db * 8 + kb] = __builtin_amdgcn_mfma_f32_16x16x32_bf16(a[db], b[kb], oa[db * 8 + kb], 0, 0, 0);
        }
    }

#pragma unroll
    for (int db = 0; db < 2; ++db)
#pragma unroll
        for (int kb = 0; kb < 8; ++kb)
#pragma unroll
            for (int r = 0; r < 4; ++r) {
                int d = 32 * w + 16 * db + 4 * quad + r;
                out[((size_t)bh * D_LEN + d) * S_LEN + kb0 + kb * 16 + l16] =
                    oa[db * 8 + kb][r];
            }
}

// ================= Fallback path (ws too small) =================
__global__ __launch_bounds__(256, 3) void k_rowsum_fb(
    const float* __restrict__ x1, const float* __restrict__ x2,
    const float* __restrict__ mask, float* __restrict__ rl)
{
    __shared__ unsigned short sQ[128 * 136];
    __shared__ unsigned short sK[64 * 136];
    const int q0 = blockIdx.x * 128;
    const int bh = blockIdx.y;
    const float* x1b = x1 + (size_t)bh * S_LEN * D_LEN;
    const float* x2b = x2 + (size_t)bh * S_LEN * D_LEN;
    const int t = threadIdx.x;
    const int w = t >> 6, lane = t & 63, quad = lane >> 4, l16 = lane & 15;
#pragma unroll
    for (int i = 0; i < 16; ++i) {
        int e = (i * 256 + t) * 4;
        int r = e >> 7, c = e & 127;
        float4 v = *(const float4*)&x1b[(size_t)(q0 + r) * D_LEN + c];
        *(uint2*)&sQ[r * 136 + c] = pack4bf(v);
    }
    float rs[8] = {0.f, 0.f, 0.f, 0.f, 0.f, 0.f, 0.f, 0.f};
    for (int k0 = 0; k0 < S_LEN; k0 += 64) {
        __syncthreads();
#pragma unroll
        for (int i = 0; i < 8; ++i) {
            int e = (i * 256 + t) * 4;
            int r = e >> 7, c = e & 127;
            float4 v = *(const float4*)&x2b[(size_t)(k0 + r) * D_LEN + c];
            *(uint2*)&sK[r * 136 + c] = pack4bf(v);
        }
        __syncthreads();
#pragma unroll
        for (int qb = 0; qb < 2; ++qb) {
            const int qrow = 32 * w + 16 * qb;
#pragma unroll
            for (int kb = 0; kb < 4; ++kb) {
                f32x4 acc = {0.f, 0.f, 0.f, 0.f};
#pragma unroll
                for (int kk = 0; kk < 4; ++kk) {
                    short8 a = *(const short8*)&sQ[(qrow + l16) * 136 + kk * 32 + quad * 8];
                    short8 b = *(const short8*)&sK[(kb * 16 + l16) * 136 + kk * 32 + quad * 8];
                    acc = __builtin_amdgcn_mfma_f32_16x16x32_bf16(a, b, acc, 0, 0, 0);
                }
                const int kg = k0 + kb * 16 + l16;
                const int qg = q0 + qrow + 4 * quad;
#pragma unroll
                for (int r = 0; r < 4; ++r) {
                    float m = mask[(size_t)(qg + r) * S_LEN + kg];
                    rs[qb * 4 + r] += __expf(acc[r] * SCALE_QK + m);
                }
            }
        }
    }
#pragma unroll
    for (int i = 0; i < 8; ++i) {
        float v = rs[i];
        v += __shfl_xor(v, 1); v += __shfl_xor(v, 2);
        v += __shfl_xor(v, 4); v += __shfl_xor(v, 8);
        if (l16 == 0) {
            int qg = q0 + 32 * w + 16 * (i >> 2) + 4 * quad + (i & 3);
            rl[(size_t)bh * S_LEN + qg] = 1.0f / v;
        }
    }
}

__global__ __launch_bounds__(256, 2) void k_out_fb(
    const float* __restrict__ x1, const float* __restrict__ x2,
    const float* __restrict__ x3, const float* __restrict__ mask,
    const float* __restrict__ rl, float* __restrict__ out)
{
    __shared__ unsigned short sK[64 * 136];
    __shared__ unsigned short sQ[64 * 136];
    __shared__ unsigned short sX[128 * 72];
    __shared__ unsigned short sE[64 * 72];
    const int kb0 = blockIdx.x * 64;
    const int bh = blockIdx.y;
    const float* x1b = x1 + (size_t)bh * S_LEN * D_LEN;
    const float* x2b = x2 + (size_t)bh * S_LEN * D_LEN;
    const float* x3b = x3 + (size_t)bh * (size_t)D_LEN * S_LEN;
    const float* rlb = rl + (size_t)bh * S_LEN;
    const int t = threadIdx.x;
    const int w = t >> 6, lane = t & 63, quad = lane >> 4, l16 = lane & 15;
#pragma unroll
    for (int i = 0; i < 8; ++i) {
        int e = (i * 256 + t) * 4;
        int r = e >> 7, c = e & 127;
        float4 v = *(const float4*)&x2b[(size_t)(kb0 + r) * D_LEN + c];
        *(uint2*)&sK[r * 136 + c] = pack4bf(v);
    }
    f32x4 oa[8];
#pragma unroll
    for (int i = 0; i < 8; ++i) oa[i] = (f32x4){0.f, 0.f, 0.f, 0.f};
    for (int q0 = 0; q0 < S_LEN; q0 += 64) {
        __syncthreads();
#pragma unroll
        for (int i = 0; i < 8; ++i) {
            int e = (i * 256 + t) * 4;
            int r = e >> 7, c = e & 127;
            float4 v = *(const float4*)&x1b[(size_t)(q0 + r) * D_LEN + c];
            *(uint2*)&sQ[r * 136 + c] = pack4bf(v);
        }
#pragma unroll
        for (int i = 0; i < 8; ++i) {
            int e = (i * 256 + t) * 4;
            int r = e >> 6, c = e & 63;
            float4 v = *(const float4*)&x3b[(size_t)r * S_LEN + q0 + c];
            *(uint2*)&sX[r * 72 + c] = pack4bf(v);
        }
        __syncthreads();
        const int qrow = 16 * w + 4 * quad;
        float rl4[4];
#pragma unroll
        for (int r = 0; r < 4; ++r) rl4[r] = rlb[q0 + qrow + r];
#pragma unroll
        for (int kb = 0; kb < 4; ++kb) {
            f32x4 acc = {0.f, 0.f, 0.f, 0.f};
#pragma unroll
            for (int kk = 0; kk < 4; ++kk) {
                short8 a = *(const short8*)&sQ[(16 * w + l16) * 136 + kk * 32 + quad * 8];
                short8 b = *(const short8*)&sK[(kb * 16 + l16) * 136 + kk * 32 + quad * 8];
                acc = __builtin_amdgcn_mfma_f32_16x16x32_bf16(a, b, acc, 0, 0, 0);
            }
            const int kg = kb0 + kb * 16 + l16;
            unsigned short e4[4];
#pragma unroll
            for (int r = 0; r < 4; ++r) {
                float m = mask[(size_t)(q0 + qrow + r) * S_LEN + kg];
                e4[r] = f2bf(__expf(acc[r] * SCALE_QK + m) * rl4[r]);
            }
            uint2 pk;
            pk.x = (unsigned)e4[0] | ((unsigned)e4[1] << 16);
            pk.y = (unsigned)e4[2] | ((unsigned)e4[3] << 16);
            *(uint2*)&sE[(kb * 16 + l16) * 72 + qrow] = pk;
        }
        __syncthreads();
#pragma unroll
        for (int db = 0; db < 2; ++db)
#pragma unroll
            for (int kb = 0; kb < 4; ++kb) {
                f32x4 a0 = oa[db * 4 + kb];
#pragma unroll
                for (int kk = 0; kk < 2; ++kk) {
                    short8 a = *(const short8*)&sX[(32 * w + 16 * db + l16) * 72 + kk * 32 + quad * 8];
                    short8 b = *(const short8*)&sE[(kb * 16 + l16) * 72 + kk * 32 + quad * 8];
                    a0 = __builtin_amdgcn_mfma_f32_16x16x32_bf16(a, b, a0, 0, 0, 0);
                }
                oa[db * 4 + kb] = a0;
            }
    }
#pragma unroll
    for (int db = 0; db < 2; ++db)
#pragma unroll
        for (int kb = 0; kb < 4; ++kb)
#pragma unroll
            for (int r = 0; r < 4; ++r) {
                int d = 32 * w + 16 * db + 4 * quad + r;
                out[((size_t)bh * D_LEN + d) * S_LEN + kb0 + kb * 16 + l16] =
                    oa[db * 4 + kb][r];
            }
}

extern "C" void kernel_launch(void* const* d_in, const int* in_sizes, int n_in,
                              void* d_out, int out_size, void* d_ws, size_t ws_size,
                              hipStream_t stream) {
    const float* x1 = (const float*)d_in[0];
    const float* x2 = (const float*)d_in[1];
    const float* x3 = (const float*)d_in[2];
    const float* mask = (const float*)d_in[3];
    float* out = (float*)d_out;

    const size_t N1 = (size_t)BH_N * S_LEN * D_LEN;
    const size_t NM = (size_t)S_LEN * S_LEN;
    const size_t need = (3 * N1 + NM) * sizeof(unsigned short);  // 58.7 MB

    if (ws_size >= need) {
        unsigned short* x1s = (unsigned short*)d_ws;
        unsigned short* x2b = x1s + N1;
        unsigned short* x3s = x2b + N1;
        unsigned short* mbf = x3s + N1;
        const size_t tot4 = (2 * N1 + NM) / 4;
        k_cvt<<<dim3((unsigned)(tot4 / 256)), dim3(256), 0, stream>>>(x1, x2, mask, x1s, x2b, mbf);
        k_qk<<<dim3(S_LEN / 128, BH_N), dim3(256), 0, stream>>>(x1s, x2b, mbf, x3, x3s);
        k_out<<<dim3(S_LEN / 128, BH_N), dim3(256), 0, stream>>>(x1s, x2b, x3s, mbf, out);
    } else {
        float* rl = (float*)d_ws;
        k_rowsum_fb<<<dim3(S_LEN / 128, BH_N), dim3(256), 0, stream>>>(x1, x2, mask, rl);
        k_out_fb<<<dim3(S_LEN / 64, BH_N), dim3(256), 0, stream>>>(x1, x2, x3, mask, rl, out);
    }
}